// Round 7
// baseline (287.423 us; speedup 1.0000x reference)
//
#include <hip/hip_runtime.h>

// MHA block on gfx950: qkv = x@Wa+ba; causal attention (static softmax); out = o@Wp+bp.
// B=4, L=2048, D=1024, H=16, Hd=64. bf16 MFMA 16x16x32, fp32 accumulation.
// R7: R6 dbuf K-loop with CORRECTED BK=32 swizzle: slot(r) = seg ^ ((r>>1)&3)
// (64B rows -> bank start (16r+4s)%32; parity x slot = 8 groups x 2 lanes = free).

typedef __attribute__((ext_vector_type(8))) short short8;   // 8 bf16
typedef __attribute__((ext_vector_type(4))) short s16x4;    // 4 bf16
typedef __attribute__((ext_vector_type(4))) float f32x4;    // MFMA C/D frag

#define DEVI __device__ __forceinline__

constexpr int NE = 1024, NH = 16, NB = 4, L = 2048;
constexpr int M = NB * L;       // 8192 tokens
constexpr int KD = 1024;        // GEMM K (both GEMMs)

DEVI unsigned f2bf(float f) {
    union { float f; unsigned u; } v; v.f = f;
    unsigned u = v.u;
    u += 0x7fffu + ((u >> 16) & 1u);   // RNE
    return u >> 16;
}
DEVI unsigned pack_bf2(float lo, float hi) {   // round-half-up, 2 floats -> 1 dword
    union { float f; unsigned u; } a, b; a.f = lo; b.f = hi;
    return ((a.u + 0x8000u) >> 16) | ((b.u + 0x8000u) & 0xffff0000u);
}

typedef const __attribute__((address_space(1))) void* gas_t;
typedef __attribute__((address_space(3))) void* las_t;
DEVI void gl_lds16(const void* g, void* l) {
    __builtin_amdgcn_global_load_lds((gas_t)g, (las_t)l, 16, 0, 0);
}

// ---------- fp32 -> bf16 bulk convert (x) ----------
__global__ void k_f32_to_bf16(const float* __restrict__ in,
                              unsigned short* __restrict__ out, int n8) {
    int i = blockIdx.x * blockDim.x + threadIdx.x;
    if (i >= n8) return;
    const float4* p = (const float4*)in + (size_t)i * 2;
    float4 a = p[0], b = p[1];
    short8 r;
    r[0] = f2bf(a.x); r[1] = f2bf(a.y); r[2] = f2bf(a.z); r[3] = f2bf(a.w);
    r[4] = f2bf(b.x); r[5] = f2bf(b.y); r[6] = f2bf(b.z); r[7] = f2bf(b.w);
    ((short8*)out)[i] = r;
}

// ---------- fp32 [R][C] -> bf16 [C][R] transpose-convert (weights) ----------
__global__ void k_transpose_bf16(const float* __restrict__ in,
                                 unsigned short* __restrict__ out, int R, int C) {
    __shared__ float t[32][33];
    int x = blockIdx.x * 32 + threadIdx.x;
    int y0 = blockIdx.y * 32;
#pragma unroll
    for (int i = 0; i < 4; i++)
        t[threadIdx.y + 8 * i][threadIdx.x] = in[(size_t)(y0 + threadIdx.y + 8 * i) * C + x];
    __syncthreads();
    int xo = y0 + threadIdx.x;
    int yo = blockIdx.x * 32 + threadIdx.y;
#pragma unroll
    for (int i = 0; i < 4; i++)
        out[(size_t)(yo + 8 * i) * R + xo] = f2bf(t[threadIdx.x][threadIdx.y + 8 * i]);
}

// ---------- 128x128 bf16 GEMM, BK=32, double-buffered, single barrier/iter ----
// LDS slot s (16B) of row r holds global k-seg s^((r>>1)&3).
template <int MODE>
__global__ __launch_bounds__(256, 4)
void k_gemm(const unsigned short* __restrict__ A,
            const unsigned short* __restrict__ Bt,
            const float* __restrict__ bias,
            unsigned short* __restrict__ Qb,
            unsigned short* __restrict__ Kb,
            unsigned short* __restrict__ Vt,
            float* __restrict__ out) {
    __shared__ alignas(16) short As[2][128 * 32];   // 8 KB each
    __shared__ alignas(16) short Bs[2][128 * 32];
    const int tid = threadIdx.x;
    const int lane = tid & 63, wid = tid >> 6;
    const int quad = lane >> 4, l16 = lane & 15;
    const int wm = (wid >> 1) * 64, wn = (wid & 1) * 64;
    const int m0 = blockIdx.y * 128;
    const int n0 = blockIdx.x * 128;

    const int srow = lane >> 2;                       // 16 rows per wave-call
    const int gseg = (lane & 3) ^ ((lane >> 3) & 3);  // staging swizzle (row bases %16==0)
    const int rsw = (l16 >> 1) & 3;                   // read swizzle term

    f32x4 acc[4][4] = {};

    auto stage = [&](int buf, int kk) {
#pragma unroll
        for (int c = 0; c < 2; c++) {
            const int rb = c * 64 + wid * 16;
            gl_lds16(&A[(size_t)(m0 + rb + srow) * KD + kk + gseg * 8], &As[buf][rb * 32]);
            gl_lds16(&Bt[(size_t)(n0 + rb + srow) * KD + kk + gseg * 8], &Bs[buf][rb * 32]);
        }
    };
    auto compute = [&](int buf) {
        short8 af[4], bf[4];
#pragma unroll
        for (int t = 0; t < 4; t++) {
            const int Ra = wm + t * 16 + l16;
            af[t] = *(const short8*)&As[buf][Ra * 32 + ((quad ^ rsw) * 8)];
            const int Rb = wn + t * 16 + l16;
            bf[t] = *(const short8*)&Bs[buf][Rb * 32 + ((quad ^ rsw) * 8)];
        }
#pragma unroll
        for (int mt = 0; mt < 4; mt++)
#pragma unroll
            for (int nt = 0; nt < 4; nt++)
                acc[mt][nt] = __builtin_amdgcn_mfma_f32_16x16x32_bf16(
                    af[mt], bf[nt], acc[mt][nt], 0, 0, 0);
    };

    stage(0, 0);
    for (int kk = 0; kk < KD; kk += 64) {
        __syncthreads();                       // drains stage of buf0@kk
        if (kk + 32 < KD) stage(1, kk + 32);   // in flight during compute(0)
        compute(0);
        __syncthreads();                       // drains stage of buf1@kk+32
        if (kk + 64 < KD) stage(0, kk + 64);   // in flight during compute(1)
        compute(1);
    }

#pragma unroll
    for (int nt = 0; nt < 4; nt++) {
        const int n = n0 + wn + nt * 16 + l16;
        const float bv = bias[n];
        if (MODE == 0) {
            const int sel = n >> 10;                  // 0=Q 1=K 2=V
            const int h = (n & 1023) >> 6;
            const int d = n & 63;
#pragma unroll
            for (int mt = 0; mt < 4; mt++)
#pragma unroll
                for (int r = 0; r < 4; r++) {
                    const int m = m0 + wm + mt * 16 + quad * 4 + r;
                    const int b = m >> 11, l = m & 2047;
                    const int bh = b * NH + h;
                    const float v = acc[mt][nt][r] + bv;
                    if (sel == 0)      Qb[(size_t)(bh * L + l) * 64 + d] = f2bf(v * 0.125f);
                    else if (sel == 1) Kb[(size_t)(bh * L + l) * 64 + d] = f2bf(v);
                    else               Vt[(size_t)(bh * 64 + d) * L + l] = f2bf(v);
                }
        } else {
#pragma unroll
            for (int mt = 0; mt < 4; mt++)
#pragma unroll
                for (int r = 0; r < 4; r++) {
                    const int m = m0 + wm + mt * 16 + quad * 4 + r;
                    out[(size_t)m * NE + n] = acc[mt][nt][r] + bv;
                }
        }
    }
}

// ---------- causal attention, static softmax, S^T formulation ----------
// grid (64, 8): qt = 7 - y (LPT). Block = 256 q rows; wave owns 64.
// K/V tiles of 128 double-buffered (one barrier per tile, prefetch in flight).
__global__ __launch_bounds__(256, 2)
void k_attn(const unsigned short* __restrict__ Q,   // [BH][L][64], pre-scaled 1/8
            const unsigned short* __restrict__ Kb,  // [BH][L][64]
            const unsigned short* __restrict__ Vt,  // [BH][64][L]
            unsigned short* __restrict__ O) {       // [B][L][NE] bf16
    __shared__ alignas(16) short smem[32768];       // Ks[2][8192] | Vs[2][8192]; Os overlays
    short* Ksb = smem;
    short* Vsb = smem + 16384;
    short* Os = smem;

    const int tid = threadIdx.x;
    const int lane = tid & 63, wid = tid >> 6;
    const int quad = lane >> 4, l16 = lane & 15;
    const int bh = blockIdx.x;
    const int qt = 7 - (int)blockIdx.y;              // heavy blocks first
    const int wq0 = qt * 256 + wid * 64;
    const size_t base = (size_t)bh * L * 64;
    const int b = bh >> 4, h = bh & 15;

    short8 qf[4][2];
#pragma unroll
    for (int mt = 0; mt < 4; mt++)
#pragma unroll
        for (int dc = 0; dc < 2; dc++)
            qf[mt][dc] = *(const short8*)&Q[base + (size_t)(wq0 + mt * 16 + l16) * 64 + dc * 32 + quad * 8];

    f32x4 o[4][4] = {};
    float lrow[4] = {};

    const int ntiles = 2 * qt + 2;

    auto stage = [&](int buf, int kt) {
        short* Kc = Ksb + buf * 8192;
        short* Vc = Vsb + buf * 8192;
#pragma unroll
        for (int c = 0; c < 4; c++) {            // K tile 128x64, slot s^(row&7)
            const int rb = c * 32 + wid * 8;
            const int row = rb + (lane >> 3);
            const int gs = (lane & 7) ^ (row & 7);
            gl_lds16(&Kb[base + (size_t)(kt * 128 + row) * 64 + gs * 8], &Kc[rb * 64]);
        }
#pragma unroll
        for (int c = 0; c < 4; c++) {            // V^T tile 64x128, slot s^(row&15)
            const int rb = c * 16 + wid * 4;
            const int row = rb + (lane >> 4);
            const int gs = (lane & 15) ^ (row & 15);
            gl_lds16(&Vt[base + (size_t)row * L + kt * 128 + gs * 8], &Vc[rb * 128]);
        }
    };

    stage(0, 0);
    for (int kt = 0; kt < ntiles; kt++) {
        __syncthreads();
        if (kt + 1 < ntiles) stage((kt + 1) & 1, kt + 1);
        const short* Kc = Ksb + (kt & 1) * 8192;
        const short* Vc = Vsb + (kt & 1) * 8192;

        const int avail = wq0 + 64 - kt * 128;   // q-rows this wave still covers
        const int chunks = avail <= 0 ? 0 : (avail >= 128 ? 4 : ((avail + 31) >> 5));

        for (int kc = 0; kc < chunks; kc++) {
            short8 kf[2][2];
#pragma unroll
            for (int j0 = 0; j0 < 2; j0++)
#pragma unroll
                for (int dc = 0; dc < 2; dc++) {
                    const int R = kc * 32 + j0 * 16 + l16;
                    kf[j0][dc] = *(const short8*)&Kc[R * 64 + (((dc * 4 + quad) ^ (R & 7)) * 8)];
                }
            f32x4 st[4][2];
#pragma unroll
            for (int mt = 0; mt < 4; mt++)
#pragma unroll
                for (int j0 = 0; j0 < 2; j0++) {
                    f32x4 z = {};
                    z = __builtin_amdgcn_mfma_f32_16x16x32_bf16(kf[j0][0], qf[mt][0], z, 0, 0, 0);
                    z = __builtin_amdgcn_mfma_f32_16x16x32_bf16(kf[j0][1], qf[mt][1], z, 0, 0, 0);
                    st[mt][j0] = z;
                }
            short8 pb[4];
#pragma unroll
            for (int mt = 0; mt < 4; mt++) {
                const bool dm = (kt * 128 + kc * 32 + 31) > (wq0 + mt * 16);  // wave-uniform
                float pe[8];
                float sum = 0.f;
#pragma unroll
                for (int j0 = 0; j0 < 2; j0++)
#pragma unroll
                    for (int r = 0; r < 4; r++) {
                        float p = __expf(st[mt][j0][r]);
                        if (dm) {
                            const int kcol = kt * 128 + kc * 32 + j0 * 16 + quad * 4 + r;
                            const int q = wq0 + mt * 16 + l16;
                            if (kcol > q) p = 0.f;
                        }
                        sum += p;
                        pe[j0 * 4 + r] = p;
                    }
                lrow[mt] += sum;
#pragma unroll
                for (int w = 0; w < 4; w++) {
                    unsigned pk = pack_bf2(pe[2 * w], pe[2 * w + 1]);
                    pb[mt][2 * w] = (short)(pk & 0xffff);
                    pb[mt][2 * w + 1] = (short)(pk >> 16);
                }
            }
#pragma unroll
            for (int dt = 0; dt < 4; dt++) {
                const int R2 = dt * 16 + l16;
                const int s16a = kc * 4 + (quad >> 1);
                const int off = (quad & 1) * 4;
                s16x4 lo = *(const s16x4*)&Vc[R2 * 128 + ((s16a ^ l16) * 8) + off];
                s16x4 hi = *(const s16x4*)&Vc[R2 * 128 + (((s16a + 2) ^ l16) * 8) + off];
                short8 vf = __builtin_shufflevector(lo, hi, 0, 1, 2, 3, 4, 5, 6, 7);
#pragma unroll
                for (int mt = 0; mt < 4; mt++)
                    o[mt][dt] = __builtin_amdgcn_mfma_f32_16x16x32_bf16(
                        vf, pb[mt], o[mt][dt], 0, 0, 0);
            }
        }
    }

    float inv[4];
#pragma unroll
    for (int mt = 0; mt < 4; mt++) {
        float rs = lrow[mt];
        rs += __shfl_xor(rs, 16);
        rs += __shfl_xor(rs, 32);
        inv[mt] = 1.0f / rs;
    }

    __syncthreads();
#pragma unroll
    for (int mt = 0; mt < 4; mt++) {
        const int lr = wid * 64 + mt * 16 + l16;
#pragma unroll
        for (int dt = 0; dt < 4; dt++) {
            unsigned w0 = f2bf(o[mt][dt][0] * inv[mt]) | (f2bf(o[mt][dt][1] * inv[mt]) << 16);
            unsigned w1 = f2bf(o[mt][dt][2] * inv[mt]) | (f2bf(o[mt][dt][3] * inv[mt]) << 16);
            *(uint2*)&Os[lr * 72 + dt * 16 + quad * 4] = make_uint2(w0, w1);
        }
    }
    __syncthreads();
#pragma unroll
    for (int i = 0; i < 8; i++) {
        const int id = i * 256 + tid;
        const int row = id >> 3, seg = id & 7;
        short8 v = *(const short8*)&Os[row * 72 + seg * 8];
        const int q = qt * 256 + row;
        *(short8*)&O[(size_t)(b * L + q) * NE + h * 64 + seg * 8] = v;
    }
}

extern "C" void kernel_launch(void* const* d_in, const int* in_sizes, int n_in,
                              void* d_out, int out_size, void* d_ws, size_t ws_size,
                              hipStream_t stream) {
    const float* x  = (const float*)d_in[0];
    const float* Wa = (const float*)d_in[1];
    const float* ba = (const float*)d_in[2];
    const float* Wp = (const float*)d_in[3];
    const float* bp = (const float*)d_in[4];
    float* out = (float*)d_out;

    char* ws = (char*)d_ws;
    unsigned short* xb  = (unsigned short*)(ws);                     // 16 MB; reused as O
    unsigned short* WaT = (unsigned short*)(ws + (16u << 20));       //  6 MB
    unsigned short* WpT = (unsigned short*)(ws + (22u << 20));       //  2 MB
    unsigned short* Qb  = (unsigned short*)(ws + (24u << 20));       // 16 MB [BH][L][64]
    unsigned short* Kb  = (unsigned short*)(ws + (40u << 20));       // 16 MB [BH][L][64]
    unsigned short* Vt  = (unsigned short*)(ws + (56u << 20));       // 16 MB [BH][64][L]

    k_f32_to_bf16<<<(M * NE / 8 + 255) / 256, 256, 0, stream>>>(x, xb, M * NE / 8);
    k_transpose_bf16<<<dim3(3 * NE / 32, NE / 32), dim3(32, 8), 0, stream>>>(Wa, WaT, NE, 3 * NE);
    k_transpose_bf16<<<dim3(NE / 32, NE / 32), dim3(32, 8), 0, stream>>>(Wp, WpT, NE, NE);

    k_gemm<0><<<dim3(3 * NE / 128, M / 128), 256, 0, stream>>>(xb, WaT, ba, Qb, Kb, Vt, nullptr);

    unsigned short* Ob = xb;
    k_attn<<<dim3(NB * NH, 8), 256, 0, stream>>>(Qb, Kb, Vt, Ob);

    k_gemm<1><<<dim3(NE / 128, M / 128), 256, 0, stream>>>(Ob, WpT, bp, nullptr, nullptr, nullptr, out);
}

// Round 8
// 270.479 us; speedup vs baseline: 1.0626x; 1.0626x over previous
//
#include <hip/hip_runtime.h>

// MHA block on gfx950: qkv = x@Wa+ba; causal attention (static softmax); out = o@Wp+bp.
// B=4, L=2048, D=1024, H=16, Hd=64. bf16 MFMA 16x16x32, fp32 accumulation.
// R8: GEMM = BK=64 double-buffered, ONE barrier per BK iter (16 drains/block
// vs 32), prefetch in flight across a full 32-MFMA compute interval. 64 KB LDS
// (2 blocks/CU, matching measured residency). R5's conflict-free s^(r&7)
// swizzle verbatim. Attention unchanged from R7.

typedef __attribute__((ext_vector_type(8))) short short8;   // 8 bf16
typedef __attribute__((ext_vector_type(4))) short s16x4;    // 4 bf16
typedef __attribute__((ext_vector_type(4))) float f32x4;    // MFMA C/D frag

#define DEVI __device__ __forceinline__

constexpr int NE = 1024, NH = 16, NB = 4, L = 2048;
constexpr int M = NB * L;       // 8192 tokens
constexpr int KD = 1024;        // GEMM K (both GEMMs)

DEVI unsigned f2bf(float f) {
    union { float f; unsigned u; } v; v.f = f;
    unsigned u = v.u;
    u += 0x7fffu + ((u >> 16) & 1u);   // RNE
    return u >> 16;
}
DEVI unsigned pack_bf2(float lo, float hi) {   // round-half-up, 2 floats -> 1 dword
    union { float f; unsigned u; } a, b; a.f = lo; b.f = hi;
    return ((a.u + 0x8000u) >> 16) | ((b.u + 0x8000u) & 0xffff0000u);
}

typedef const __attribute__((address_space(1))) void* gas_t;
typedef __attribute__((address_space(3))) void* las_t;
DEVI void gl_lds16(const void* g, void* l) {
    __builtin_amdgcn_global_load_lds((gas_t)g, (las_t)l, 16, 0, 0);
}

// ---------- fp32 -> bf16 bulk convert (x) ----------
__global__ void k_f32_to_bf16(const float* __restrict__ in,
                              unsigned short* __restrict__ out, int n8) {
    int i = blockIdx.x * blockDim.x + threadIdx.x;
    if (i >= n8) return;
    const float4* p = (const float4*)in + (size_t)i * 2;
    float4 a = p[0], b = p[1];
    short8 r;
    r[0] = f2bf(a.x); r[1] = f2bf(a.y); r[2] = f2bf(a.z); r[3] = f2bf(a.w);
    r[4] = f2bf(b.x); r[5] = f2bf(b.y); r[6] = f2bf(b.z); r[7] = f2bf(b.w);
    ((short8*)out)[i] = r;
}

// ---------- fp32 [R][C] -> bf16 [C][R] transpose-convert (weights) ----------
__global__ void k_transpose_bf16(const float* __restrict__ in,
                                 unsigned short* __restrict__ out, int R, int C) {
    __shared__ float t[32][33];
    int x = blockIdx.x * 32 + threadIdx.x;
    int y0 = blockIdx.y * 32;
#pragma unroll
    for (int i = 0; i < 4; i++)
        t[threadIdx.y + 8 * i][threadIdx.x] = in[(size_t)(y0 + threadIdx.y + 8 * i) * C + x];
    __syncthreads();
    int xo = y0 + threadIdx.x;
    int yo = blockIdx.x * 32 + threadIdx.y;
#pragma unroll
    for (int i = 0; i < 4; i++)
        out[(size_t)(yo + 8 * i) * R + xo] = f2bf(t[threadIdx.x][threadIdx.y + 8 * i]);
}

// ---------- 128x128 bf16 GEMM, BK=64, double-buffered, 1 barrier/BK-iter ----
// LDS slot s (16B) of row r holds global k-seg s^(r&7) (conflict-free, R5).
template <int MODE>
__global__ __launch_bounds__(256, 2)
void k_gemm(const unsigned short* __restrict__ A,
            const unsigned short* __restrict__ Bt,
            const float* __restrict__ bias,
            unsigned short* __restrict__ Qb,
            unsigned short* __restrict__ Kb,
            unsigned short* __restrict__ Vt,
            float* __restrict__ out) {
    __shared__ alignas(16) short As[2][128 * 64];   // 16 KB each
    __shared__ alignas(16) short Bs[2][128 * 64];
    const int tid = threadIdx.x;
    const int lane = tid & 63, wid = tid >> 6;
    const int quad = lane >> 4, l16 = lane & 15;
    const int wm = (wid >> 1) * 64, wn = (wid & 1) * 64;
    const int m0 = blockIdx.y * 128;
    const int n0 = blockIdx.x * 128;

    const int srow = lane >> 3;              // 8 rows per wave-call
    const int gseg = (lane & 7) ^ srow;      // staging swizzle (row bases %8==0)

    f32x4 acc[4][4] = {};

    auto stage = [&](int buf, int kk) {
#pragma unroll
        for (int c = 0; c < 4; c++) {
            const int rb = c * 32 + wid * 8;
            gl_lds16(&A[(size_t)(m0 + rb + srow) * KD + kk + gseg * 8], &As[buf][rb * 64]);
            gl_lds16(&Bt[(size_t)(n0 + rb + srow) * KD + kk + gseg * 8], &Bs[buf][rb * 64]);
        }
    };
    auto compute = [&](int buf) {
#pragma unroll
        for (int kc = 0; kc < 2; kc++) {
            short8 af[4], bf[4];
#pragma unroll
            for (int t = 0; t < 4; t++) {
                const int Ra = wm + t * 16 + l16;
                af[t] = *(const short8*)&As[buf][Ra * 64 + (((kc * 4 + quad) ^ (Ra & 7)) * 8)];
                const int Rb = wn + t * 16 + l16;
                bf[t] = *(const short8*)&Bs[buf][Rb * 64 + (((kc * 4 + quad) ^ (Rb & 7)) * 8)];
            }
#pragma unroll
            for (int mt = 0; mt < 4; mt++)
#pragma unroll
                for (int nt = 0; nt < 4; nt++)
                    acc[mt][nt] = __builtin_amdgcn_mfma_f32_16x16x32_bf16(
                        af[mt], bf[nt], acc[mt][nt], 0, 0, 0);
        }
    };

    stage(0, 0);
    int buf = 0;
    for (int kk = 0; kk < KD; kk += 64) {
        __syncthreads();                        // drains stage(buf)@kk; frees buf^1 reads
        if (kk + 64 < KD) stage(buf ^ 1, kk + 64);  // in flight during compute(buf)
        compute(buf);
        buf ^= 1;
    }

#pragma unroll
    for (int nt = 0; nt < 4; nt++) {
        const int n = n0 + wn + nt * 16 + l16;
        const float bv = bias[n];
        if (MODE == 0) {
            const int sel = n >> 10;                  // 0=Q 1=K 2=V
            const int h = (n & 1023) >> 6;
            const int d = n & 63;
#pragma unroll
            for (int mt = 0; mt < 4; mt++)
#pragma unroll
                for (int r = 0; r < 4; r++) {
                    const int m = m0 + wm + mt * 16 + quad * 4 + r;
                    const int b = m >> 11, l = m & 2047;
                    const int bh = b * NH + h;
                    const float v = acc[mt][nt][r] + bv;
                    if (sel == 0)      Qb[(size_t)(bh * L + l) * 64 + d] = f2bf(v * 0.125f);
                    else if (sel == 1) Kb[(size_t)(bh * L + l) * 64 + d] = f2bf(v);
                    else               Vt[(size_t)(bh * 64 + d) * L + l] = f2bf(v);
                }
        } else {
#pragma unroll
            for (int mt = 0; mt < 4; mt++)
#pragma unroll
                for (int r = 0; r < 4; r++) {
                    const int m = m0 + wm + mt * 16 + quad * 4 + r;
                    out[(size_t)m * NE + n] = acc[mt][nt][r] + bv;
                }
        }
    }
}

// ---------- causal attention, static softmax, S^T formulation (R7) ----------
// grid (64, 8): qt = 7 - y (LPT). Block = 256 q rows; wave owns 64.
// K/V tiles of 128 double-buffered (one barrier per tile, prefetch in flight).
__global__ __launch_bounds__(256, 2)
void k_attn(const unsigned short* __restrict__ Q,   // [BH][L][64], pre-scaled 1/8
            const unsigned short* __restrict__ Kb,  // [BH][L][64]
            const unsigned short* __restrict__ Vt,  // [BH][64][L]
            unsigned short* __restrict__ O) {       // [B][L][NE] bf16
    __shared__ alignas(16) short smem[32768];       // Ks[2][8192] | Vs[2][8192]; Os overlays
    short* Ksb = smem;
    short* Vsb = smem + 16384;
    short* Os = smem;

    const int tid = threadIdx.x;
    const int lane = tid & 63, wid = tid >> 6;
    const int quad = lane >> 4, l16 = lane & 15;
    const int bh = blockIdx.x;
    const int qt = 7 - (int)blockIdx.y;              // heavy blocks first
    const int wq0 = qt * 256 + wid * 64;
    const size_t base = (size_t)bh * L * 64;
    const int b = bh >> 4, h = bh & 15;

    short8 qf[4][2];
#pragma unroll
    for (int mt = 0; mt < 4; mt++)
#pragma unroll
        for (int dc = 0; dc < 2; dc++)
            qf[mt][dc] = *(const short8*)&Q[base + (size_t)(wq0 + mt * 16 + l16) * 64 + dc * 32 + quad * 8];

    f32x4 o[4][4] = {};
    float lrow[4] = {};

    const int ntiles = 2 * qt + 2;

    auto stage = [&](int buf, int kt) {
        short* Kc = Ksb + buf * 8192;
        short* Vc = Vsb + buf * 8192;
#pragma unroll
        for (int c = 0; c < 4; c++) {            // K tile 128x64, slot s^(row&7)
            const int rb = c * 32 + wid * 8;
            const int row = rb + (lane >> 3);
            const int gs = (lane & 7) ^ (row & 7);
            gl_lds16(&Kb[base + (size_t)(kt * 128 + row) * 64 + gs * 8], &Kc[rb * 64]);
        }
#pragma unroll
        for (int c = 0; c < 4; c++) {            // V^T tile 64x128, slot s^(row&15)
            const int rb = c * 16 + wid * 4;
            const int row = rb + (lane >> 4);
            const int gs = (lane & 15) ^ (row & 15);
            gl_lds16(&Vt[base + (size_t)row * L + kt * 128 + gs * 8], &Vc[rb * 128]);
        }
    };

    stage(0, 0);
    for (int kt = 0; kt < ntiles; kt++) {
        __syncthreads();
        if (kt + 1 < ntiles) stage((kt + 1) & 1, kt + 1);
        const short* Kc = Ksb + (kt & 1) * 8192;
        const short* Vc = Vsb + (kt & 1) * 8192;

        const int avail = wq0 + 64 - kt * 128;   // q-rows this wave still covers
        const int chunks = avail <= 0 ? 0 : (avail >= 128 ? 4 : ((avail + 31) >> 5));

        for (int kc = 0; kc < chunks; kc++) {
            short8 kf[2][2];
#pragma unroll
            for (int j0 = 0; j0 < 2; j0++)
#pragma unroll
                for (int dc = 0; dc < 2; dc++) {
                    const int R = kc * 32 + j0 * 16 + l16;
                    kf[j0][dc] = *(const short8*)&Kc[R * 64 + (((dc * 4 + quad) ^ (R & 7)) * 8)];
                }
            f32x4 st[4][2];
#pragma unroll
            for (int mt = 0; mt < 4; mt++)
#pragma unroll
                for (int j0 = 0; j0 < 2; j0++) {
                    f32x4 z = {};
                    z = __builtin_amdgcn_mfma_f32_16x16x32_bf16(kf[j0][0], qf[mt][0], z, 0, 0, 0);
                    z = __builtin_amdgcn_mfma_f32_16x16x32_bf16(kf[j0][1], qf[mt][1], z, 0, 0, 0);
                    st[mt][j0] = z;
                }
            short8 pb[4];
#pragma unroll
            for (int mt = 0; mt < 4; mt++) {
                const bool dm = (kt * 128 + kc * 32 + 31) > (wq0 + mt * 16);  // wave-uniform
                float pe[8];
                float sum = 0.f;
#pragma unroll
                for (int j0 = 0; j0 < 2; j0++)
#pragma unroll
                    for (int r = 0; r < 4; r++) {
                        float p = __expf(st[mt][j0][r]);
                        if (dm) {
                            const int kcol = kt * 128 + kc * 32 + j0 * 16 + quad * 4 + r;
                            const int q = wq0 + mt * 16 + l16;
                            if (kcol > q) p = 0.f;
                        }
                        sum += p;
                        pe[j0 * 4 + r] = p;
                    }
                lrow[mt] += sum;
#pragma unroll
                for (int w = 0; w < 4; w++) {
                    unsigned pk = pack_bf2(pe[2 * w], pe[2 * w + 1]);
                    pb[mt][2 * w] = (short)(pk & 0xffff);
                    pb[mt][2 * w + 1] = (short)(pk >> 16);
                }
            }
#pragma unroll
            for (int dt = 0; dt < 4; dt++) {
                const int R2 = dt * 16 + l16;
                const int s16a = kc * 4 + (quad >> 1);
                const int off = (quad & 1) * 4;
                s16x4 lo = *(const s16x4*)&Vc[R2 * 128 + ((s16a ^ l16) * 8) + off];
                s16x4 hi = *(const s16x4*)&Vc[R2 * 128 + (((s16a + 2) ^ l16) * 8) + off];
                short8 vf = __builtin_shufflevector(lo, hi, 0, 1, 2, 3, 4, 5, 6, 7);
#pragma unroll
                for (int mt = 0; mt < 4; mt++)
                    o[mt][dt] = __builtin_amdgcn_mfma_f32_16x16x32_bf16(
                        vf, pb[mt], o[mt][dt], 0, 0, 0);
            }
        }
    }

    float inv[4];
#pragma unroll
    for (int mt = 0; mt < 4; mt++) {
        float rs = lrow[mt];
        rs += __shfl_xor(rs, 16);
        rs += __shfl_xor(rs, 32);
        inv[mt] = 1.0f / rs;
    }

    __syncthreads();
#pragma unroll
    for (int mt = 0; mt < 4; mt++) {
        const int lr = wid * 64 + mt * 16 + l16;
#pragma unroll
        for (int dt = 0; dt < 4; dt++) {
            unsigned w0 = f2bf(o[mt][dt][0] * inv[mt]) | (f2bf(o[mt][dt][1] * inv[mt]) << 16);
            unsigned w1 = f2bf(o[mt][dt][2] * inv[mt]) | (f2bf(o[mt][dt][3] * inv[mt]) << 16);
            *(uint2*)&Os[lr * 72 + dt * 16 + quad * 4] = make_uint2(w0, w1);
        }
    }
    __syncthreads();
#pragma unroll
    for (int i = 0; i < 8; i++) {
        const int id = i * 256 + tid;
        const int row = id >> 3, seg = id & 7;
        short8 v = *(const short8*)&Os[row * 72 + seg * 8];
        const int q = qt * 256 + row;
        *(short8*)&O[(size_t)(b * L + q) * NE + h * 64 + seg * 8] = v;
    }
}

extern "C" void kernel_launch(void* const* d_in, const int* in_sizes, int n_in,
                              void* d_out, int out_size, void* d_ws, size_t ws_size,
                              hipStream_t stream) {
    const float* x  = (const float*)d_in[0];
    const float* Wa = (const float*)d_in[1];
    const float* ba = (const float*)d_in[2];
    const float* Wp = (const float*)d_in[3];
    const float* bp = (const float*)d_in[4];
    float* out = (float*)d_out;

    char* ws = (char*)d_ws;
    unsigned short* xb  = (unsigned short*)(ws);                     // 16 MB; reused as O
    unsigned short* WaT = (unsigned short*)(ws + (16u << 20));       //  6 MB
    unsigned short* WpT = (unsigned short*)(ws + (22u << 20));       //  2 MB
    unsigned short* Qb  = (unsigned short*)(ws + (24u << 20));       // 16 MB [BH][L][64]
    unsigned short* Kb  = (unsigned short*)(ws + (40u << 20));       // 16 MB [BH][L][64]
    unsigned short* Vt  = (unsigned short*)(ws + (56u << 20));       // 16 MB [BH][64][L]

    k_f32_to_bf16<<<(M * NE / 8 + 255) / 256, 256, 0, stream>>>(x, xb, M * NE / 8);
    k_transpose_bf16<<<dim3(3 * NE / 32, NE / 32), dim3(32, 8), 0, stream>>>(Wa, WaT, NE, 3 * NE);
    k_transpose_bf16<<<dim3(NE / 32, NE / 32), dim3(32, 8), 0, stream>>>(Wp, WpT, NE, NE);

    k_gemm<0><<<dim3(3 * NE / 128, M / 128), 256, 0, stream>>>(xb, WaT, ba, Qb, Kb, Vt, nullptr);

    unsigned short* Ob = xb;
    k_attn<<<dim3(NB * NH, 8), 256, 0, stream>>>(Qb, Kb, Vt, Ob);

    k_gemm<1><<<dim3(NE / 128, M / 128), 256, 0, stream>>>(Ob, WpT, bp, nullptr, nullptr, nullptr, out);
}